// Round 1
// baseline (180.154 us; speedup 1.0000x reference)
//
#include <hip/hip_runtime.h>
#include <hip/hip_bf16.h>

typedef __attribute__((ext_vector_type(4))) float f32x4;
typedef __attribute__((ext_vector_type(8))) short bf16x8;

#define H 1024        // hidden / K
#define NTOT 1280     // nq*64 + nkv*64*2
#define BM 128
#define BN 128
#define BK 64

static __device__ __forceinline__ unsigned short f2bf(float f) {
    __hip_bfloat16 b = __float2bfloat16(f);
    return __builtin_bit_cast(unsigned short, b);
}

#define GLOAD_LDS16(g, l)                                                     \
    __builtin_amdgcn_global_load_lds(                                         \
        (const __attribute__((address_space(1))) void*)(g),                   \
        (__attribute__((address_space(3))) void*)(l), 16, 0, 0)

// ---------------------------------------------------------------------------
// Kernel 1: RMSNorm rows of x (fp32) -> h (bf16). One wave per row.
// (1 + ln_w) is folded into the weights, NOT here.
// ---------------------------------------------------------------------------
__global__ __launch_bounds__(256) void k_rms(const float* __restrict__ x,
                                             __hip_bfloat16* __restrict__ h) {
    const int wave = threadIdx.x >> 6;
    const int lane = threadIdx.x & 63;
    const size_t row = (size_t)blockIdx.x * 4 + wave;

    const float4* xr = (const float4*)(x + row * H);
    float4 v[4];
    float ss = 0.f;
#pragma unroll
    for (int i = 0; i < 4; ++i) {
        v[i] = xr[lane + 64 * i];
        ss += v[i].x * v[i].x + v[i].y * v[i].y + v[i].z * v[i].z + v[i].w * v[i].w;
    }
#pragma unroll
    for (int o = 1; o < 64; o <<= 1) ss += __shfl_xor(ss, o);
    const float sc = rsqrtf(ss * (1.0f / H) + 1e-6f);

    ushort4* hr = (ushort4*)(h + row * H);
#pragma unroll
    for (int i = 0; i < 4; ++i) {
        ushort4 o4;
        o4.x = f2bf(v[i].x * sc);
        o4.y = f2bf(v[i].y * sc);
        o4.z = f2bf(v[i].z * sc);
        o4.w = f2bf(v[i].w * sc);
        hr[lane + 64 * i] = o4;
    }
}

// ---------------------------------------------------------------------------
// Kernel 2: build transposed fused weight Bt[n][k] = bf16((1+lnw[k]) * W[k][n])
// n in [0,1024) -> wq, [1024,1152) -> wk, [1152,1280) -> wv
// ---------------------------------------------------------------------------
__global__ __launch_bounds__(256) void k_wprep(const float* __restrict__ wq,
                                               const float* __restrict__ wk,
                                               const float* __restrict__ wv,
                                               const float* __restrict__ lnw,
                                               __hip_bfloat16* __restrict__ Bt) {
    const int idx = blockIdx.x * 256 + threadIdx.x;  // idx = n*1024 + k
    const int n = idx >> 10;
    const int k = idx & 1023;
    const float s = 1.0f + lnw[k];
    float w;
    if (n < 1024)       w = wq[k * 1024 + n];
    else if (n < 1152)  w = wk[k * 128 + (n - 1024)];
    else                w = wv[k * 128 + (n - 1152)];
    Bt[idx] = __float2bfloat16(s * w);
}

// ---------------------------------------------------------------------------
// Kernel 3: GEMM  out[M][1280] = h[M][1024] @ Bt^T, split-region epilogue.
// 128x128 tile, BK=64, 4 waves (2x2), double-buffered LDS, global_load_lds x16.
// ---------------------------------------------------------------------------
__global__ __launch_bounds__(256) void k_gemm(const __hip_bfloat16* __restrict__ A,
                                              const __hip_bfloat16* __restrict__ Bt,
                                              float* __restrict__ out, int rows) {
    __shared__ short lds[2][2 * BM * BK];  // per buf: A tile [128][64], B tile [128][64]

    const int tid = threadIdx.x;
    const int nt = blockIdx.x % 10;
    const int mt = blockIdx.x / 10;
    const size_t m0 = (size_t)mt * BM;
    const int lane = tid & 63;
    const int wid = tid >> 6;
    const int wm = wid >> 1, wn = wid & 1;

    // staging source base: thread t covers row t/8, 8 bf16 at col (t%8)*8
    const __hip_bfloat16* agp = A + (m0 + tid / 8) * (size_t)H + (tid % 8) * 8;
    const __hip_bfloat16* bgp = Bt + ((size_t)nt * BN + tid / 8) * (size_t)H + (tid % 8) * 8;

#define STAGE(buf, kt)                                                        \
    {                                                                         \
        const size_t koff = (size_t)(kt) * BK;                                \
        _Pragma("unroll") for (int i = 0; i < 4; ++i) {                       \
            GLOAD_LDS16(agp + (size_t)(i * 32) * H + koff,                    \
                        &lds[buf][i * 2048 + tid * 8]);                       \
            GLOAD_LDS16(bgp + (size_t)(i * 32) * H + koff,                    \
                        &lds[buf][BM * BK + i * 2048 + tid * 8]);             \
        }                                                                     \
    }

    f32x4 acc[4][4] = {};
    const int arow = wm * 64 + (lane & 15);
    const int brow = wn * 64 + (lane & 15);
    const int kq = (lane >> 4) * 8;

    STAGE(0, 0);
    __syncthreads();

    const int nk = H / BK;  // 16
    for (int kt = 0; kt < nk; ++kt) {
        const int cur = kt & 1;
        if (kt + 1 < nk) STAGE(cur ^ 1, kt + 1);

        const short* al = &lds[cur][0];
        const short* bl = &lds[cur][BM * BK];
#pragma unroll
        for (int ks = 0; ks < BK; ks += 32) {
            bf16x8 af[4], bfv[4];
#pragma unroll
            for (int mi = 0; mi < 4; ++mi)
                af[mi] = *(const bf16x8*)(al + (arow + mi * 16) * BK + ks + kq);
#pragma unroll
            for (int ni = 0; ni < 4; ++ni)
                bfv[ni] = *(const bf16x8*)(bl + (brow + ni * 16) * BK + ks + kq);
#pragma unroll
            for (int mi = 0; mi < 4; ++mi)
#pragma unroll
                for (int ni = 0; ni < 4; ++ni)
                    acc[mi][ni] = __builtin_amdgcn_mfma_f32_16x16x32_bf16(
                        af[mi], bfv[ni], acc[mi][ni], 0, 0, 0);
        }
        __syncthreads();
    }

    // epilogue: split q/k/v regions (tile-aligned: nt 0-7 -> q, 8 -> k, 9 -> v)
    const size_t QSZ = (size_t)rows * 1024;
    const size_t KSZ = (size_t)rows * 128;
    float* op;
    int ldc, col0;
    if (nt < 8)      { op = out;             ldc = 1024; col0 = nt * 128; }
    else if (nt == 8){ op = out + QSZ;       ldc = 128;  col0 = 0; }
    else             { op = out + QSZ + KSZ; ldc = 128;  col0 = 0; }

    const size_t crow0 = m0 + wm * 64 + ((lane >> 4) * 4);
    const int ccol0 = col0 + wn * 64 + (lane & 15);
#pragma unroll
    for (int mi = 0; mi < 4; ++mi)
#pragma unroll
        for (int ni = 0; ni < 4; ++ni)
#pragma unroll
            for (int r = 0; r < 4; ++r)
                op[(crow0 + mi * 16 + r) * (size_t)ldc + ccol0 + ni * 16] = acc[mi][ni][r];
}

// ---------------------------------------------------------------------------
extern "C" void kernel_launch(void* const* d_in, const int* in_sizes, int n_in,
                              void* d_out, int out_size, void* d_ws, size_t ws_size,
                              hipStream_t stream) {
    const float* x   = (const float*)d_in[0];
    const float* lnw = (const float*)d_in[1];
    const float* wq  = (const float*)d_in[2];
    const float* wk  = (const float*)d_in[3];
    const float* wv  = (const float*)d_in[4];
    float* out = (float*)d_out;

    const int rows = in_sizes[0] / H;  // B*S = 32768

    __hip_bfloat16* Bt = (__hip_bfloat16*)d_ws;                       // 1280*1024*2 = 2.62 MB
    __hip_bfloat16* h  = (__hip_bfloat16*)((char*)d_ws + (size_t)NTOT * H * 2);  // rows*1024*2

    k_wprep<<<NTOT * H / 256, 256, 0, stream>>>(wq, wk, wv, lnw, Bt);
    k_rms<<<rows / 4, 256, 0, stream>>>(x, h);
    k_gemm<<<(rows / BM) * (NTOT / BN), 256, 0, stream>>>(h, Bt, out, rows);
}

// Round 2
// 155.504 us; speedup vs baseline: 1.1585x; 1.1585x over previous
//
#include <hip/hip_runtime.h>
#include <hip/hip_bf16.h>

typedef __attribute__((ext_vector_type(4))) float f32x4;
typedef __attribute__((ext_vector_type(8))) short bf16x8;

#define H 1024        // hidden / K
#define NTOT 1280     // nq*64 + nkv*64*2
#define BM 256
#define BN 256
#define BK 64
#define NKT (H / BK)  // 16 K-tiles

static __device__ __forceinline__ unsigned short f2bf(float f) {
    __hip_bfloat16 b = __float2bfloat16(f);
    return __builtin_bit_cast(unsigned short, b);
}

#define GLOAD_LDS16(g, l)                                                     \
    __builtin_amdgcn_global_load_lds(                                         \
        (const __attribute__((address_space(1))) void*)(g),                   \
        (__attribute__((address_space(3))) void*)(l), 16, 0, 0)

// ---------------------------------------------------------------------------
// Kernel 1: RMSNorm rows of x (fp32) -> h (bf16). One wave per row.
// ---------------------------------------------------------------------------
__global__ __launch_bounds__(256) void k_rms(const float* __restrict__ x,
                                             __hip_bfloat16* __restrict__ h) {
    const int wave = threadIdx.x >> 6;
    const int lane = threadIdx.x & 63;
    const size_t row = (size_t)blockIdx.x * 4 + wave;

    const float4* xr = (const float4*)(x + row * H);
    float4 v[4];
    float ss = 0.f;
#pragma unroll
    for (int i = 0; i < 4; ++i) {
        v[i] = xr[lane + 64 * i];
        ss += v[i].x * v[i].x + v[i].y * v[i].y + v[i].z * v[i].z + v[i].w * v[i].w;
    }
#pragma unroll
    for (int o = 1; o < 64; o <<= 1) ss += __shfl_xor(ss, o);
    const float sc = rsqrtf(ss * (1.0f / H) + 1e-6f);

    ushort4* hr = (ushort4*)(h + row * H);
#pragma unroll
    for (int i = 0; i < 4; ++i) {
        ushort4 o4;
        o4.x = f2bf(v[i].x * sc);
        o4.y = f2bf(v[i].y * sc);
        o4.z = f2bf(v[i].z * sc);
        o4.w = f2bf(v[i].w * sc);
        hr[lane + 64 * i] = o4;
    }
}

// ---------------------------------------------------------------------------
// Kernel 2: build transposed fused weight Bt[n][k] = bf16((1+lnw[k]) * W[k][n])
// ---------------------------------------------------------------------------
__global__ __launch_bounds__(256) void k_wprep(const float* __restrict__ wq,
                                               const float* __restrict__ wk,
                                               const float* __restrict__ wv,
                                               const float* __restrict__ lnw,
                                               __hip_bfloat16* __restrict__ Bt) {
    const int idx = blockIdx.x * 256 + threadIdx.x;  // idx = n*1024 + k
    const int n = idx >> 10;
    const int k = idx & 1023;
    const float s = 1.0f + lnw[k];
    float w;
    if (n < 1024)       w = wq[k * 1024 + n];
    else if (n < 1152)  w = wk[k * 128 + (n - 1024)];
    else                w = wv[k * 128 + (n - 1152)];
    Bt[idx] = __float2bfloat16(s * w);
}

// ---------------------------------------------------------------------------
// Kernel 3: GEMM out[M][1280] = h[M][1024] @ Bt^T.
// 256x256 tile, BK=64, 8 waves (2M x 4N), 512 threads.
// Ring-2 LDS (128 KiB), counted vmcnt (loads in flight across barriers),
// T2 XOR swizzle (row&7)<<4 applied pre-swizzled-global + swizzled-ds_read.
// Per iteration: [vmcnt(8); bar] -> ds_read kk0 frags -> MFMA kk0
//                -> ds_read kk1 frags -> [lgkm(0); bar] -> STAGE(kt+2, same slot)
//                -> MFMA kk1.
// ---------------------------------------------------------------------------
__global__ __launch_bounds__(512, 2) void k_gemm(const __hip_bfloat16* __restrict__ A,
                                                 const __hip_bfloat16* __restrict__ Bt,
                                                 float* __restrict__ out, int rows) {
    __shared__ __align__(16) char smem[131072];  // 2 bufs x (A 32KB | B 32KB)

    const int tid = threadIdx.x;
    const int lane = tid & 63;
    const int wid = tid >> 6;
    const int wm = wid >> 2;   // 0..1
    const int wn = wid & 3;    // 0..3

    // --- bijective XCD chunk swizzle (m204), nt fastest so A-strip sharers
    // land on the same XCD's L2 ---
    const int nwg = gridDim.x;
    const int q8 = nwg >> 3, r8 = nwg & 7;
    const int xcd = blockIdx.x & 7, rank = blockIdx.x >> 3;
    const int wg = (xcd < r8 ? xcd * (q8 + 1) : r8 * (q8 + 1) + (xcd - r8) * q8) + rank;
    const int nt = wg % (NTOT / BN);   // 0..4
    const int mt = wg / (NTOT / BN);
    const size_t m0 = (size_t)mt * BM;

    // --- staging addresses: thread t covers LDS row t/8 (+j*64), 16B at (t%8)*16.
    // Global source col is pre-swizzled by ((row&7)<<4) so linear LDS dest +
    // swizzled ds_read form a consistent involution (rule 21). ---
    const int cswz = ((tid & 7) * 16) ^ (((tid >> 3) & 7) << 4);
    const char* aG = (const char*)A + (m0 + (tid >> 3)) * (size_t)(H * 2) + cswz;
    const char* bG = (const char*)Bt + ((size_t)nt * BN + (tid >> 3)) * (size_t)(H * 2) + cswz;

#define STAGE(buf, kt)                                                        \
    {                                                                         \
        const char* as_ = aG + (size_t)(kt) * (BK * 2);                       \
        const char* bs_ = bG + (size_t)(kt) * (BK * 2);                       \
        char* ld_ = smem + (buf) * 65536 + tid * 16;                          \
        _Pragma("unroll") for (int j = 0; j < 4; ++j)                         \
            GLOAD_LDS16(as_ + (size_t)j * 64 * (H * 2), ld_ + j * 8192);      \
        _Pragma("unroll") for (int j = 0; j < 4; ++j)                         \
            GLOAD_LDS16(bs_ + (size_t)j * 64 * (H * 2), ld_ + 32768 + j * 8192); \
    }

    // --- fragment read addressing (swizzled) ---
    const int rowA = wm * 128 + (lane & 15);
    const int rowB = wn * 64 + (lane & 15);
    const int xm = (lane & 7) << 4;
    const int c0 = (((lane >> 4) * 16)) ^ xm;        // kk=0 col bytes
    const int c1 = (64 + ((lane >> 4) * 16)) ^ xm;   // kk=1 col bytes

    f32x4 acc[8][4] = {};

    STAGE(0, 0);
    STAGE(1, 1);

#define ITER(kt, DOSTAGE, VMSTR)                                              \
    {                                                                         \
        const int cur_ = (kt) & 1;                                            \
        const char* aLb = smem + cur_ * 65536;                                \
        const char* bLb = aLb + 32768;                                        \
        asm volatile("s_waitcnt vmcnt(" VMSTR ")" ::: "memory");              \
        __builtin_amdgcn_s_barrier();                                         \
        __builtin_amdgcn_sched_barrier(0);                                    \
        bf16x8 a0[8], b0[4];                                                  \
        _Pragma("unroll") for (int mi = 0; mi < 8; ++mi)                      \
            a0[mi] = *(const bf16x8*)(aLb + (rowA + mi * 16) * 128 + c0);     \
        _Pragma("unroll") for (int ni = 0; ni < 4; ++ni)                      \
            b0[ni] = *(const bf16x8*)(bLb + (rowB + ni * 16) * 128 + c0);     \
        _Pragma("unroll") for (int mi = 0; mi < 8; ++mi)                      \
            _Pragma("unroll") for (int ni = 0; ni < 4; ++ni)                  \
                acc[mi][ni] = __builtin_amdgcn_mfma_f32_16x16x32_bf16(        \
                    a0[mi], b0[ni], acc[mi][ni], 0, 0, 0);                    \
        bf16x8 a1[8], b1[4];                                                  \
        _Pragma("unroll") for (int mi = 0; mi < 8; ++mi)                      \
            a1[mi] = *(const bf16x8*)(aLb + (rowA + mi * 16) * 128 + c1);     \
        _Pragma("unroll") for (int ni = 0; ni < 4; ++ni)                      \
            b1[ni] = *(const bf16x8*)(bLb + (rowB + ni * 16) * 128 + c1);     \
        asm volatile("s_waitcnt lgkmcnt(0)" ::: "memory");                    \
        __builtin_amdgcn_s_barrier();                                         \
        __builtin_amdgcn_sched_barrier(0);                                    \
        if (DOSTAGE) STAGE(cur_, (kt) + 2);                                   \
        _Pragma("unroll") for (int mi = 0; mi < 8; ++mi)                      \
            _Pragma("unroll") for (int ni = 0; ni < 4; ++ni)                  \
                acc[mi][ni] = __builtin_amdgcn_mfma_f32_16x16x32_bf16(        \
                    a1[mi], b1[ni], acc[mi][ni], 0, 0, 0);                    \
    }

#pragma unroll 2
    for (int kt = 0; kt < NKT - 2; ++kt) ITER(kt, true, "8");
    ITER(NKT - 2, false, "8");
    ITER(NKT - 1, false, "0");

    // --- epilogue: split q/k/v regions. BN=256 chunks of wn*64 never straddle
    // the 1024/1152 boundaries. ---
    const size_t QSZ = (size_t)rows * 1024;
    const size_t KSZ = (size_t)rows * 128;
    const int colg0 = nt * BN + wn * 64;
    float* op;
    int ldc, cb0;
    if (colg0 < 1024)      { op = out;             ldc = 1024; cb0 = colg0; }
    else if (colg0 < 1152) { op = out + QSZ;       ldc = 128;  cb0 = colg0 - 1024; }
    else                   { op = out + QSZ + KSZ; ldc = 128;  cb0 = colg0 - 1152; }

    const size_t r0 = m0 + wm * 128 + ((lane >> 4) * 4);
    const int cc0 = cb0 + (lane & 15);
#pragma unroll
    for (int mi = 0; mi < 8; ++mi)
#pragma unroll
        for (int ni = 0; ni < 4; ++ni)
#pragma unroll
            for (int r = 0; r < 4; ++r)
                op[(r0 + mi * 16 + r) * (size_t)ldc + cc0 + ni * 16] = acc[mi][ni][r];
}

// ---------------------------------------------------------------------------
extern "C" void kernel_launch(void* const* d_in, const int* in_sizes, int n_in,
                              void* d_out, int out_size, void* d_ws, size_t ws_size,
                              hipStream_t stream) {
    const float* x   = (const float*)d_in[0];
    const float* lnw = (const float*)d_in[1];
    const float* wq  = (const float*)d_in[2];
    const float* wk  = (const float*)d_in[3];
    const float* wv  = (const float*)d_in[4];
    float* out = (float*)d_out;

    const int rows = in_sizes[0] / H;  // B*S = 32768

    __hip_bfloat16* Bt = (__hip_bfloat16*)d_ws;                               // 2.62 MB
    __hip_bfloat16* h  = (__hip_bfloat16*)((char*)d_ws + (size_t)NTOT * H * 2);

    k_wprep<<<NTOT * H / 256, 256, 0, stream>>>(wq, wk, wv, lnw, Bt);
    k_rms<<<rows / 4, 256, 0, stream>>>(x, h);
    k_gemm<<<(rows / BM) * (NTOT / BN), 512, 0, stream>>>(h, Bt, out, rows);
}